// Round 14
// baseline (424.903 us; speedup 1.0000x reference)
//
#include <hip/hip_runtime.h>
#include <stdint.h>

#define NN 50000
#define EE 800000
#define ET 850000
#define INC 128
#define HID 256
#define OUTC 128
#define NB ((NN + 255) / 256)     // 196 scan blocks
#define GDEG ((ET + 255) / 256)   // 3321 degree blocks
#define GTRP 640                  // transpose blocks (128+256+256)

typedef __attribute__((ext_vector_type(4))) float f32x4;
typedef __attribute__((ext_vector_type(8))) short s16x8;
typedef __attribute__((ext_vector_type(4))) short s16x4;

static __device__ __forceinline__ float b2f(unsigned short u){
  union { float f; unsigned int i; } v; v.i = ((unsigned int)u) << 16; return v.f;
}
static __device__ __forceinline__ unsigned short f2b(float f){
  union { float f; unsigned int i; } v; v.f = f;
  unsigned int r = v.i + 0x7FFFu + ((v.i >> 16) & 1u);
  return (unsigned short)(r >> 16);
}

// ---------------- fused init: degree atomics (saving per-edge rank) + W transposes + pool zero ----------------
__global__ void k_init(const int* __restrict__ ei, int* __restrict__ cnt,
                       int* __restrict__ pos,
                       const float* __restrict__ W1, const float* __restrict__ W2,
                       const float* __restrict__ W3, unsigned short* __restrict__ T1,
                       unsigned short* __restrict__ T2, unsigned short* __restrict__ T3,
                       float* __restrict__ pool){
  int b = blockIdx.x, tid = threadIdx.x;
  if (b < GDEG){
    int e = b * 256 + tid;
    if (e < ET){
      int d = (e < EE) ? ei[EE + e] : (e - EE);
      pos[e] = atomicAdd(&cnt[d], 1);     // rank of edge within its dst node
    }
  } else if (b < GDEG + GTRP){
    int bb = b - GDEG;
    const float* W; unsigned short* WT; int K, base;
    if (bb < 128)      { W = W1; WT = T1; K = 128; base = 0; }
    else if (bb < 384) { W = W2; WT = T2; K = 256; base = 128; }
    else               { W = W3; WT = T3; K = 256; base = 384; }
    int idx = (bb - base) * 256 + tid;
    int k = idx >> 8, c = idx & 255;
    WT[c * K + k] = f2b(W[idx]);
  } else {
    pool[tid] = 0.f;
  }
}

// per-block exclusive scan + block sums
__global__ void k_blockscan(const int* __restrict__ cnt, int* __restrict__ off,
                            int* __restrict__ bsum){
  __shared__ int s[256];
  int b = blockIdx.x, tid = threadIdx.x;
  int i = b * 256 + tid;
  int v = (i < NN) ? cnt[i] : 0;
  s[tid] = v; __syncthreads();
  #pragma unroll
  for (int o = 1; o < 256; o <<= 1){
    int t = (tid >= o) ? s[tid - o] : 0; __syncthreads();
    s[tid] += t; __syncthreads();
  }
  if (i < NN) off[i] = s[tid] - v;        // block-local exclusive offsets
  if (tid == 255) bsum[b] = s[255];
}

__global__ void k_scanb(const int* __restrict__ bsum, int* __restrict__ bbase){
  __shared__ int s[256];
  int tid = threadIdx.x;
  int v = (tid < NB) ? bsum[tid] : 0;
  s[tid] = v; __syncthreads();
  #pragma unroll
  for (int o = 1; o < 256; o <<= 1){
    int t = (tid >= o) ? s[tid - o] : 0; __syncthreads();
    s[tid] += t; __syncthreads();
  }
  if (tid < NB) bbase[tid] = s[tid] - v;
}

// scatter: atomic-free (uses precomputed per-edge rank)
__global__ void k_scatter(const int* __restrict__ ei, const int* __restrict__ off,
                          const int* __restrict__ bbase, const int* __restrict__ pos,
                          int* __restrict__ ssrc){
  int e = blockIdx.x * 256 + threadIdx.x;
  if (e >= ET) return;
  int s, d;
  if (e < EE){ s = ei[e]; d = ei[EE + e]; } else { s = e - EE; d = s; }
  ssrc[off[d] + bbase[d >> 8] + pos[e]] = s;
}

// ---------------- LDS-free, barrier-free MFMA GEMM (32x256 tile) + shuffle alpha epilogue ----------------
// Each wave loads its A fragments straight from global (L2-hit; 4x redundancy per
// block is ~3us of L2 traffic) and B from the L2-resident WT. No LDS, no barriers:
// pure load/MFMA stream, latency hidden by TLP. K compile-time -> T fully unrolled.
template<bool AF32, int KV>
__global__ __launch_bounds__(256) void k_gemm_fused(const void* __restrict__ Av,
    const unsigned short* __restrict__ WT,
    const float* __restrict__ a_src, const float* __restrict__ a_dst,
    unsigned short* __restrict__ C, float* __restrict__ as_, float* __restrict__ ad_,
    int M){
  constexpr int T = KV >> 6;
  int tid = threadIdx.x;
  int wave = tid >> 6, lane = tid & 63;
  int bm0 = blockIdx.x * 32;
  int wc0 = wave * 64;
  f32x4 acc[2][4];
  #pragma unroll
  for (int i = 0; i < 2; i++)
    #pragma unroll
    for (int j = 0; j < 4; j++) acc[i][j] = (f32x4){0.f, 0.f, 0.f, 0.f};

  // A rows this lane needs (clamped: rows >= M read row M-1, outputs discarded)
  int ra0 = min(bm0 + (lane & 15), M - 1);
  int ra1 = min(bm0 + 16 + (lane & 15), M - 1);
  int klo = (lane >> 4) * 8;                 // k-chunk within 32-wide half

  #pragma unroll
  for (int t = 0; t < T; t++){
    s16x8 af[2][2], bf[2][4];
    #pragma unroll
    for (int half = 0; half < 2; half++){
      int kl = t * 64 + half * 32 + klo;
      if constexpr (AF32){
        const float* A = (const float*)Av;
        const float4* p0 = (const float4*)(A + (size_t)ra0 * KV + kl);
        const float4* p1 = (const float4*)(A + (size_t)ra1 * KV + kl);
        float4 v0 = p0[0], v1 = p0[1], v2 = p1[0], v3 = p1[1];
        unsigned short t0[8] = {f2b(v0.x), f2b(v0.y), f2b(v0.z), f2b(v0.w),
                                f2b(v1.x), f2b(v1.y), f2b(v1.z), f2b(v1.w)};
        unsigned short t1[8] = {f2b(v2.x), f2b(v2.y), f2b(v2.z), f2b(v2.w),
                                f2b(v3.x), f2b(v3.y), f2b(v3.z), f2b(v3.w)};
        af[half][0] = *(s16x8*)t0;
        af[half][1] = *(s16x8*)t1;
      } else {
        const unsigned short* A = (const unsigned short*)Av;
        af[half][0] = *(const s16x8*)(A + (size_t)ra0 * KV + kl);
        af[half][1] = *(const s16x8*)(A + (size_t)ra1 * KV + kl);
      }
      #pragma unroll
      for (int ni = 0; ni < 4; ni++)
        bf[half][ni] = *(const s16x8*)(WT + (size_t)(wc0 + ni * 16 + (lane & 15)) * KV + kl);
    }
    #pragma unroll
    for (int half = 0; half < 2; half++)
      #pragma unroll
      for (int mi = 0; mi < 2; mi++)
        #pragma unroll
        for (int ni = 0; ni < 4; ni++)
          acc[mi][ni] = __builtin_amdgcn_mfma_f32_16x16x32_bf16(af[half][mi], bf[half][ni], acc[mi][ni], 0, 0, 0);
  }

  // C write direct from acc
  #pragma unroll
  for (int mi = 0; mi < 2; mi++){
    #pragma unroll
    for (int ni = 0; ni < 4; ni++){
      int col = wc0 + ni * 16 + (lane & 15);
      int rb = mi * 16 + (lane >> 4) * 4;
      #pragma unroll
      for (int r = 0; r < 4; r++){
        int row = rb + r;
        if (bm0 + row < M) C[(size_t)(bm0 + row) * HID + col] = f2b(acc[mi][ni][r]);
      }
    }
  }
  // alpha epilogue: per-lane partial dot over ni, 16-lane shfl_xor reduce
  float asv[4], adv[4];
  #pragma unroll
  for (int ni = 0; ni < 4; ni++){
    int d = wc0 + ni * 16 + (lane & 15);
    asv[ni] = a_src[d];
    adv[ni] = a_dst[d];
  }
  #pragma unroll
  for (int mi = 0; mi < 2; mi++){
    #pragma unroll
    for (int r = 0; r < 4; r++){
      float ps = 0.f, pd = 0.f;
      #pragma unroll
      for (int ni = 0; ni < 4; ni++){
        float cv = acc[mi][ni][r];
        ps += cv * asv[ni];
        pd += cv * adv[ni];
      }
      #pragma unroll
      for (int m = 1; m < 16; m <<= 1){
        ps += __shfl_xor(ps, m, 64);
        pd += __shfl_xor(pd, m, 64);
      }
      int row = bm0 + mi * 16 + (lane >> 4) * 4 + r;
      if ((lane & 15) == 0 && row < M){
        as_[(size_t)row * 4 + wave] = ps;
        ad_[(size_t)row * 4 + wave] = pd;
      }
    }
  }
}

// ---------------- aggregation: 4-edge unroll, 1-iter load slack (R9/R13 form) ----------------
__global__ __launch_bounds__(256) void k_aggregate(const int* __restrict__ off,
    const int* __restrict__ bbase, const int* __restrict__ ssrc,
    const float* __restrict__ as_, const float* __restrict__ ad_,
    const unsigned short* __restrict__ h, const float* __restrict__ bias,
    unsigned short* __restrict__ out){
  int gid = blockIdx.x * 256 + threadIdx.x;
  int wid = gid >> 6, lane = gid & 63;
  if (wid >= NN) return;
  int start = off[wid] + bbase[wid >> 8];
  int end = (wid + 1 < NN) ? (off[wid + 1] + bbase[(wid + 1) >> 8]) : ET;
  int e1 = end - 1;
  int hq = lane >> 4;
  float ad2 = ad_[(size_t)wid * 4 + hq];
  float sA_ = 0.f, sB_ = 0.f;
  f32x4 A = {0,0,0,0}, B = {0,0,0,0}, Cc = {0,0,0,0}, D = {0,0,0,0};

  int p = start;
  int j0 = ssrc[p];
  int j1 = ssrc[min(p + 1, e1)], j2 = ssrc[min(p + 2, e1)], j3 = ssrc[min(p + 3, e1)];
  int j4 = ssrc[min(p + 4, e1)], j5 = ssrc[min(p + 5, e1)];
  int j6 = ssrc[min(p + 6, e1)], j7 = ssrc[min(p + 7, e1)];
  s16x4 r0 = *(const s16x4*)(h + (size_t)j0 * HID + lane * 4);
  s16x4 r1 = *(const s16x4*)(h + (size_t)j1 * HID + lane * 4);
  s16x4 r2 = *(const s16x4*)(h + (size_t)j2 * HID + lane * 4);
  s16x4 r3 = *(const s16x4*)(h + (size_t)j3 * HID + lane * 4);
  float a0 = as_[(size_t)j0 * 4 + hq], a1 = as_[(size_t)j1 * 4 + hq];
  float a2 = as_[(size_t)j2 * 4 + hq], a3 = as_[(size_t)j3 * 4 + hq];

  // steady state: all prefetch indices p+8..p+11 in range, no clamps
  for (; p + 11 < end; p += 4){
    s16x4 u0 = *(const s16x4*)(h + (size_t)j4 * HID + lane * 4);
    s16x4 u1 = *(const s16x4*)(h + (size_t)j5 * HID + lane * 4);
    s16x4 u2 = *(const s16x4*)(h + (size_t)j6 * HID + lane * 4);
    s16x4 u3 = *(const s16x4*)(h + (size_t)j7 * HID + lane * 4);
    float b0 = as_[(size_t)j4 * 4 + hq], b1 = as_[(size_t)j5 * 4 + hq];
    float b2 = as_[(size_t)j6 * 4 + hq], b3 = as_[(size_t)j7 * 4 + hq];
    int t0 = ssrc[p + 8], t1 = ssrc[p + 9], t2 = ssrc[p + 10], t3 = ssrc[p + 11];
    float l0 = a0 + ad2; l0 = fmaxf(l0, 0.2f * l0);
    float l1 = a1 + ad2; l1 = fmaxf(l1, 0.2f * l1);
    float l2 = a2 + ad2; l2 = fmaxf(l2, 0.2f * l2);
    float l3 = a3 + ad2; l3 = fmaxf(l3, 0.2f * l3);
    float w0 = __expf(l0), w1 = __expf(l1), w2 = __expf(l2), w3 = __expf(l3);
    sA_ += w0 + w2; sB_ += w1 + w3;
    #pragma unroll
    for (int c = 0; c < 4; c++){
      A[c]  += w0 * b2f((unsigned short)r0[c]);
      B[c]  += w1 * b2f((unsigned short)r1[c]);
      Cc[c] += w2 * b2f((unsigned short)r2[c]);
      D[c]  += w3 * b2f((unsigned short)r3[c]);
    }
    j0 = j4; j1 = j5; j2 = j6; j3 = j7;
    j4 = t0; j5 = t1; j6 = t2; j7 = t3;
    r0 = u0; r1 = u1; r2 = u2; r3 = u3;
    a0 = b0; a1 = b1; a2 = b2; a3 = b3;
  }
  // drain: clamped prefetch
  for (; p + 3 < end; p += 4){
    s16x4 u0 = *(const s16x4*)(h + (size_t)j4 * HID + lane * 4);
    s16x4 u1 = *(const s16x4*)(h + (size_t)j5 * HID + lane * 4);
    s16x4 u2 = *(const s16x4*)(h + (size_t)j6 * HID + lane * 4);
    s16x4 u3 = *(const s16x4*)(h + (size_t)j7 * HID + lane * 4);
    float b0 = as_[(size_t)j4 * 4 + hq], b1 = as_[(size_t)j5 * 4 + hq];
    float b2 = as_[(size_t)j6 * 4 + hq], b3 = as_[(size_t)j7 * 4 + hq];
    int t0 = ssrc[min(p + 8, e1)],  t1 = ssrc[min(p + 9, e1)];
    int t2 = ssrc[min(p + 10, e1)], t3 = ssrc[min(p + 11, e1)];
    float l0 = a0 + ad2; l0 = fmaxf(l0, 0.2f * l0);
    float l1 = a1 + ad2; l1 = fmaxf(l1, 0.2f * l1);
    float l2 = a2 + ad2; l2 = fmaxf(l2, 0.2f * l2);
    float l3 = a3 + ad2; l3 = fmaxf(l3, 0.2f * l3);
    float w0 = __expf(l0), w1 = __expf(l1), w2 = __expf(l2), w3 = __expf(l3);
    sA_ += w0 + w2; sB_ += w1 + w3;
    #pragma unroll
    for (int c = 0; c < 4; c++){
      A[c]  += w0 * b2f((unsigned short)r0[c]);
      B[c]  += w1 * b2f((unsigned short)r1[c]);
      Cc[c] += w2 * b2f((unsigned short)r2[c]);
      D[c]  += w3 * b2f((unsigned short)r3[c]);
    }
    j0 = j4; j1 = j5; j2 = j6; j3 = j7;
    j4 = t0; j5 = t1; j6 = t2; j7 = t3;
    r0 = u0; r1 = u1; r2 = u2; r3 = u3;
    a0 = b0; a1 = b1; a2 = b2; a3 = b3;
  }
  int rem = end - p;                                   // 0..3
  if (rem > 0){
    float l = a0 + ad2; l = fmaxf(l, 0.2f * l);
    float w = __expf(l); sA_ += w;
    #pragma unroll
    for (int c = 0; c < 4; c++) A[c]  += w * b2f((unsigned short)r0[c]);
  }
  if (rem > 1){
    float l = a1 + ad2; l = fmaxf(l, 0.2f * l);
    float w = __expf(l); sB_ += w;
    #pragma unroll
    for (int c = 0; c < 4; c++) B[c]  += w * b2f((unsigned short)r1[c]);
  }
  if (rem > 2){
    float l = a2 + ad2; l = fmaxf(l, 0.2f * l);
    float w = __expf(l); sA_ += w;
    #pragma unroll
    for (int c = 0; c < 4; c++) Cc[c] += w * b2f((unsigned short)r2[c]);
  }

  float inv = 1.f / (sA_ + sB_ + 1e-16f);
  float4 bv = *(const float4*)(bias + lane * 4);
  float o0 = (A[0] + B[0] + Cc[0] + D[0]) * inv + bv.x;
  float o1 = (A[1] + B[1] + Cc[1] + D[1]) * inv + bv.y;
  float o2 = (A[2] + B[2] + Cc[2] + D[2]) * inv + bv.z;
  float o3 = (A[3] + B[3] + Cc[3] + D[3]) * inv + bv.w;
  o0 = o0 > 0.f ? o0 : (__expf(o0) - 1.f);
  o1 = o1 > 0.f ? o1 : (__expf(o1) - 1.f);
  o2 = o2 > 0.f ? o2 : (__expf(o2) - 1.f);
  o3 = o3 > 0.f ? o3 : (__expf(o3) - 1.f);
  s16x4 ov;
  ov[0] = (short)f2b(o0); ov[1] = (short)f2b(o1);
  ov[2] = (short)f2b(o2); ov[3] = (short)f2b(o3);
  *(s16x4*)(out + (size_t)wid * HID + lane * 4) = ov;
}

// ---------------- mean pool (plain atomics) + tiny head ----------------
__global__ __launch_bounds__(256) void k_pool(const unsigned short* __restrict__ X,
                                              float* __restrict__ pool){
  int b = blockIdx.x, c = threadIdx.x;
  int n0 = b * 64, n1 = min(n0 + 64, NN);
  float acc = 0.f;
  for (int n = n0; n < n1; n++) acc += b2f(X[(size_t)n * HID + c]);
  atomicAdd(&pool[c], acc);
}

__global__ void k_head(const float* __restrict__ pool, const float* __restrict__ hW,
                       const float* __restrict__ hb, float* __restrict__ outp){
  int o = threadIdx.x;             // 128
  float acc = hb[o];
  const float invN = 1.f / (float)NN;
  for (int c = 0; c < HID; c++) acc += pool[c] * invN * hW[c * OUTC + o];
  outp[o] = acc;
}

extern "C" void kernel_launch(void* const* d_in, const int* in_sizes, int n_in,
                              void* d_out, int out_size, void* d_ws, size_t ws_size,
                              hipStream_t stream){
  const float* x  = (const float*)d_in[0];
  const int* ei   = (const int*)d_in[1];
  const float* W[3]   = {(const float*)d_in[2],  (const float*)d_in[6],  (const float*)d_in[10]};
  const float* Asr[3] = {(const float*)d_in[3],  (const float*)d_in[7],  (const float*)d_in[11]};
  const float* Adt[3] = {(const float*)d_in[4],  (const float*)d_in[8],  (const float*)d_in[12]};
  const float* B[3]   = {(const float*)d_in[5],  (const float*)d_in[9],  (const float*)d_in[13]};
  const float* hW = (const float*)d_in[14];
  const float* hb = (const float*)d_in[15];

  char* w = (char*)d_ws; size_t o = 0;
  auto alloc = [&](size_t b) -> void* { void* p = w + o; o = (o + b + 255) & ~(size_t)255; return p; };
  int* cnt  = (int*)alloc((size_t)NN * 4);
  int* off  = (int*)alloc((size_t)NN * 4);
  int* ssrc = (int*)alloc((size_t)ET * 4);
  int* pos  = (int*)alloc((size_t)ET * 4);
  int* bsum = (int*)alloc((size_t)NB * 4);
  int* bbase= (int*)alloc((size_t)NB * 4);
  unsigned short* hbuf = (unsigned short*)alloc((size_t)NN * HID * 2);
  float* as_ = (float*)alloc((size_t)NN * 4 * 4);
  float* ad_ = (float*)alloc((size_t)NN * 4 * 4);
  unsigned short* X0 = (unsigned short*)alloc((size_t)NN * HID * 2);
  unsigned short* X1 = (unsigned short*)alloc((size_t)NN * HID * 2);
  unsigned short* WT1 = (unsigned short*)alloc((size_t)INC * HID * 2);
  unsigned short* WT2 = (unsigned short*)alloc((size_t)HID * HID * 2);
  unsigned short* WT3 = (unsigned short*)alloc((size_t)HID * HID * 2);
  float* pool = (float*)alloc(256 * 4);

  hipMemsetAsync(cnt, 0, (size_t)NN * 4, stream);
  k_init<<<GDEG + GTRP + 1, 256, 0, stream>>>(ei, cnt, pos, W[0], W[1], W[2], WT1, WT2, WT3, pool);
  k_blockscan<<<NB, 256, 0, stream>>>(cnt, off, bsum);
  k_scanb<<<1, 256, 0, stream>>>(bsum, bbase);
  k_scatter<<<GDEG, 256, 0, stream>>>(ei, off, bbase, pos, ssrc);

  unsigned short* outbuf[3] = {X0, X1, X0};
  int gB = (NN + 63) / 64;          // pool blocks
  int gG = (NN + 31) / 32;          // gemm blocks (BM=32)
  int gW = (NN * 64 + 255) / 256;

  // layer 1: f32 input, K=128
  k_gemm_fused<true, 128><<<gG, 256, 0, stream>>>((const void*)x, WT1, Asr[0], Adt[0], hbuf, as_, ad_, NN);
  k_aggregate<<<gW, 256, 0, stream>>>(off, bbase, ssrc, as_, ad_, hbuf, B[0], outbuf[0]);
  // layer 2: bf16 input, K=256
  k_gemm_fused<false, 256><<<gG, 256, 0, stream>>>((const void*)outbuf[0], WT2, Asr[1], Adt[1], hbuf, as_, ad_, NN);
  k_aggregate<<<gW, 256, 0, stream>>>(off, bbase, ssrc, as_, ad_, hbuf, B[1], outbuf[1]);
  // layer 3: bf16 input, K=256
  k_gemm_fused<false, 256><<<gG, 256, 0, stream>>>((const void*)outbuf[1], WT3, Asr[2], Adt[2], hbuf, as_, ad_, NN);
  k_aggregate<<<gW, 256, 0, stream>>>(off, bbase, ssrc, as_, ad_, hbuf, B[2], outbuf[2]);

  k_pool<<<gB, 256, 0, stream>>>(X0, pool);
  k_head<<<1, 128, 0, stream>>>(pool, hW, hb, (float*)d_out);
}

// Round 15
// 395.853 us; speedup vs baseline: 1.0734x; 1.0734x over previous
//
#include <hip/hip_runtime.h>
#include <stdint.h>

#define NN 50000
#define EE 800000
#define ET 850000
#define INC 128
#define HID 256
#define OUTC 128
#define NB ((NN + 255) / 256)     // 196 scan blocks
#define GDEG ((ET + 255) / 256)   // 3321 degree blocks
#define GTRP 640                  // transpose blocks (128+256+256)

typedef __attribute__((ext_vector_type(4))) float f32x4;
typedef __attribute__((ext_vector_type(8))) short s16x8;
typedef __attribute__((ext_vector_type(4))) short s16x4;

static __device__ __forceinline__ float b2f(unsigned short u){
  union { float f; unsigned int i; } v; v.i = ((unsigned int)u) << 16; return v.f;
}
static __device__ __forceinline__ unsigned short f2b(float f){
  union { float f; unsigned int i; } v; v.f = f;
  unsigned int r = v.i + 0x7FFFu + ((v.i >> 16) & 1u);
  return (unsigned short)(r >> 16);
}

// ---------------- fused init: degree atomics (saving per-edge rank) + W transposes + pool zero ----------------
__global__ void k_init(const int* __restrict__ ei, int* __restrict__ cnt,
                       int* __restrict__ pos,
                       const float* __restrict__ W1, const float* __restrict__ W2,
                       const float* __restrict__ W3, unsigned short* __restrict__ T1,
                       unsigned short* __restrict__ T2, unsigned short* __restrict__ T3,
                       float* __restrict__ pool){
  int b = blockIdx.x, tid = threadIdx.x;
  if (b < GDEG){
    int e = b * 256 + tid;
    if (e < ET){
      int d = (e < EE) ? ei[EE + e] : (e - EE);
      pos[e] = atomicAdd(&cnt[d], 1);     // rank of edge within its dst node
    }
  } else if (b < GDEG + GTRP){
    int bb = b - GDEG;
    const float* W; unsigned short* WT; int K, base;
    if (bb < 128)      { W = W1; WT = T1; K = 128; base = 0; }
    else if (bb < 384) { W = W2; WT = T2; K = 256; base = 128; }
    else               { W = W3; WT = T3; K = 256; base = 384; }
    int idx = (bb - base) * 256 + tid;
    int k = idx >> 8, c = idx & 255;
    WT[c * K + k] = f2b(W[idx]);
  } else {
    pool[tid] = 0.f;
  }
}

// per-block exclusive scan + block sums
__global__ void k_blockscan(const int* __restrict__ cnt, int* __restrict__ off,
                            int* __restrict__ bsum){
  __shared__ int s[256];
  int b = blockIdx.x, tid = threadIdx.x;
  int i = b * 256 + tid;
  int v = (i < NN) ? cnt[i] : 0;
  s[tid] = v; __syncthreads();
  #pragma unroll
  for (int o = 1; o < 256; o <<= 1){
    int t = (tid >= o) ? s[tid - o] : 0; __syncthreads();
    s[tid] += t; __syncthreads();
  }
  if (i < NN) off[i] = s[tid] - v;        // block-local exclusive offsets
  if (tid == 255) bsum[b] = s[255];
}

__global__ void k_scanb(const int* __restrict__ bsum, int* __restrict__ bbase){
  __shared__ int s[256];
  int tid = threadIdx.x;
  int v = (tid < NB) ? bsum[tid] : 0;
  s[tid] = v; __syncthreads();
  #pragma unroll
  for (int o = 1; o < 256; o <<= 1){
    int t = (tid >= o) ? s[tid - o] : 0; __syncthreads();
    s[tid] += t; __syncthreads();
  }
  if (tid < NB) bbase[tid] = s[tid] - v;
}

// scatter: atomic-free (uses precomputed per-edge rank)
__global__ void k_scatter(const int* __restrict__ ei, const int* __restrict__ off,
                          const int* __restrict__ bbase, const int* __restrict__ pos,
                          int* __restrict__ ssrc){
  int e = blockIdx.x * 256 + threadIdx.x;
  if (e >= ET) return;
  int s, d;
  if (e < EE){ s = ei[e]; d = ei[EE + e]; } else { s = e - EE; d = s; }
  ssrc[off[d] + bbase[d >> 8] + pos[e]] = s;
}

// ---------------- fused MFMA GEMM (32x256 tile, LDS dbuf) + shuffle alpha epilogue ----------------
template<bool AF32>
__global__ __launch_bounds__(256) void k_gemm_fused(const void* __restrict__ Av,
    const unsigned short* __restrict__ WT,
    const float* __restrict__ a_src, const float* __restrict__ a_dst,
    unsigned short* __restrict__ C, float* __restrict__ as_, float* __restrict__ ad_,
    int M, int K){
  __shared__ unsigned short sA[2][32][72];               // 9216 B
  int tid = threadIdx.x;
  int wave = tid >> 6, lane = tid & 63;
  int bm0 = blockIdx.x * 32;
  int wc0 = wave * 64;
  f32x4 acc[2][4];
  #pragma unroll
  for (int i = 0; i < 2; i++)
    #pragma unroll
    for (int j = 0; j < 4; j++) acc[i][j] = (f32x4){0.f, 0.f, 0.f, 0.f};

  s16x8 rg;
  int r0 = tid >> 3, kb0 = (tid & 7) * 8;     // 32 rows x 8 chunks

  auto ldA = [&](int k0){
    int gr = bm0 + r0;
    if constexpr (AF32){
      const float* A = (const float*)Av;
      unsigned short t[8] = {0,0,0,0,0,0,0,0};
      if (gr < M){
        const float4* p = (const float4*)(A + (size_t)gr * K + k0 + kb0);
        float4 v0 = p[0], v1 = p[1];
        t[0]=f2b(v0.x); t[1]=f2b(v0.y); t[2]=f2b(v0.z); t[3]=f2b(v0.w);
        t[4]=f2b(v1.x); t[5]=f2b(v1.y); t[6]=f2b(v1.z); t[7]=f2b(v1.w);
      }
      rg = *(s16x8*)t;
    } else {
      const unsigned short* A = (const unsigned short*)Av;
      s16x8 v = (s16x8){0,0,0,0,0,0,0,0};
      if (gr < M) v = *(const s16x8*)(A + (size_t)gr * K + k0 + kb0);
      rg = v;
    }
  };

  int T = K >> 6;
  ldA(0); *(s16x8*)&sA[0][r0][kb0] = rg;
  __syncthreads();
  for (int t = 0; t < T; t++){
    int k0 = t << 6;
    if (t + 1 < T) ldA(k0 + 64);            // prefetch next A tile
    int cur = t & 1;
    s16x8 af[2][2], bf[2][4];
    #pragma unroll
    for (int half = 0; half < 2; half++){
      int kl = half * 32 + (lane >> 4) * 8;
      af[half][0] = *(const s16x8*)&sA[cur][lane & 15][kl];
      af[half][1] = *(const s16x8*)&sA[cur][16 + (lane & 15)][kl];
      #pragma unroll
      for (int ni = 0; ni < 4; ni++)
        bf[half][ni] = *(const s16x8*)(WT + (size_t)(wc0 + ni * 16 + (lane & 15)) * K + k0 + kl);
    }
    #pragma unroll
    for (int half = 0; half < 2; half++)
      #pragma unroll
      for (int mi = 0; mi < 2; mi++)
        #pragma unroll
        for (int ni = 0; ni < 4; ni++)
          acc[mi][ni] = __builtin_amdgcn_mfma_f32_16x16x32_bf16(af[half][mi], bf[half][ni], acc[mi][ni], 0, 0, 0);
    if (t + 1 < T) *(s16x8*)&sA[cur ^ 1][r0][kb0] = rg;
    __syncthreads();
  }

  // C write direct from acc
  #pragma unroll
  for (int mi = 0; mi < 2; mi++){
    #pragma unroll
    for (int ni = 0; ni < 4; ni++){
      int col = wc0 + ni * 16 + (lane & 15);
      int rb = mi * 16 + (lane >> 4) * 4;
      #pragma unroll
      for (int r = 0; r < 4; r++){
        int row = rb + r;
        if (bm0 + row < M) C[(size_t)(bm0 + row) * HID + col] = f2b(acc[mi][ni][r]);
      }
    }
  }
  // alpha epilogue: per-lane partial dot over ni, 16-lane shfl_xor reduce
  float asv[4], adv[4];
  #pragma unroll
  for (int ni = 0; ni < 4; ni++){
    int d = wc0 + ni * 16 + (lane & 15);
    asv[ni] = a_src[d];
    adv[ni] = a_dst[d];
  }
  #pragma unroll
  for (int mi = 0; mi < 2; mi++){
    #pragma unroll
    for (int r = 0; r < 4; r++){
      float ps = 0.f, pd = 0.f;
      #pragma unroll
      for (int ni = 0; ni < 4; ni++){
        float cv = acc[mi][ni][r];
        ps += cv * asv[ni];
        pd += cv * adv[ni];
      }
      #pragma unroll
      for (int m = 1; m < 16; m <<= 1){
        ps += __shfl_xor(ps, m, 64);
        pd += __shfl_xor(pd, m, 64);
      }
      int row = bm0 + mi * 16 + (lane >> 4) * 4 + r;
      if ((lane & 15) == 0 && row < M){
        as_[(size_t)row * 4 + wave] = ps;
        ad_[(size_t)row * 4 + wave] = pd;
      }
    }
  }
}

// ---------------- aggregation: 1 node per 64-thread block (no straggler coupling) ----------------
__global__ __launch_bounds__(64) void k_aggregate(const int* __restrict__ off,
    const int* __restrict__ bbase, const int* __restrict__ ssrc,
    const float* __restrict__ as_, const float* __restrict__ ad_,
    const unsigned short* __restrict__ h, const float* __restrict__ bias,
    unsigned short* __restrict__ out){
  int wid = blockIdx.x, lane = threadIdx.x;
  int start = off[wid] + bbase[wid >> 8];
  int end = (wid + 1 < NN) ? (off[wid + 1] + bbase[(wid + 1) >> 8]) : ET;
  int e1 = end - 1;
  int hq = lane >> 4;
  float ad2 = ad_[(size_t)wid * 4 + hq];
  float sA_ = 0.f, sB_ = 0.f;
  f32x4 A = {0,0,0,0}, B = {0,0,0,0}, Cc = {0,0,0,0}, D = {0,0,0,0};

  int p = start;
  int j0 = ssrc[p];
  int j1 = ssrc[min(p + 1, e1)], j2 = ssrc[min(p + 2, e1)], j3 = ssrc[min(p + 3, e1)];
  int j4 = ssrc[min(p + 4, e1)], j5 = ssrc[min(p + 5, e1)];
  int j6 = ssrc[min(p + 6, e1)], j7 = ssrc[min(p + 7, e1)];
  s16x4 r0 = *(const s16x4*)(h + (size_t)j0 * HID + lane * 4);
  s16x4 r1 = *(const s16x4*)(h + (size_t)j1 * HID + lane * 4);
  s16x4 r2 = *(const s16x4*)(h + (size_t)j2 * HID + lane * 4);
  s16x4 r3 = *(const s16x4*)(h + (size_t)j3 * HID + lane * 4);
  float a0 = as_[(size_t)j0 * 4 + hq], a1 = as_[(size_t)j1 * 4 + hq];
  float a2 = as_[(size_t)j2 * 4 + hq], a3 = as_[(size_t)j3 * 4 + hq];

  // steady state: all prefetch indices p+8..p+11 in range, no clamps
  for (; p + 11 < end; p += 4){
    s16x4 u0 = *(const s16x4*)(h + (size_t)j4 * HID + lane * 4);
    s16x4 u1 = *(const s16x4*)(h + (size_t)j5 * HID + lane * 4);
    s16x4 u2 = *(const s16x4*)(h + (size_t)j6 * HID + lane * 4);
    s16x4 u3 = *(const s16x4*)(h + (size_t)j7 * HID + lane * 4);
    float b0 = as_[(size_t)j4 * 4 + hq], b1 = as_[(size_t)j5 * 4 + hq];
    float b2 = as_[(size_t)j6 * 4 + hq], b3 = as_[(size_t)j7 * 4 + hq];
    int t0 = ssrc[p + 8], t1 = ssrc[p + 9], t2 = ssrc[p + 10], t3 = ssrc[p + 11];
    float l0 = a0 + ad2; l0 = fmaxf(l0, 0.2f * l0);
    float l1 = a1 + ad2; l1 = fmaxf(l1, 0.2f * l1);
    float l2 = a2 + ad2; l2 = fmaxf(l2, 0.2f * l2);
    float l3 = a3 + ad2; l3 = fmaxf(l3, 0.2f * l3);
    float w0 = __expf(l0), w1 = __expf(l1), w2 = __expf(l2), w3 = __expf(l3);
    sA_ += w0 + w2; sB_ += w1 + w3;
    #pragma unroll
    for (int c = 0; c < 4; c++){
      A[c]  += w0 * b2f((unsigned short)r0[c]);
      B[c]  += w1 * b2f((unsigned short)r1[c]);
      Cc[c] += w2 * b2f((unsigned short)r2[c]);
      D[c]  += w3 * b2f((unsigned short)r3[c]);
    }
    j0 = j4; j1 = j5; j2 = j6; j3 = j7;
    j4 = t0; j5 = t1; j6 = t2; j7 = t3;
    r0 = u0; r1 = u1; r2 = u2; r3 = u3;
    a0 = b0; a1 = b1; a2 = b2; a3 = b3;
  }
  // drain: clamped prefetch
  for (; p + 3 < end; p += 4){
    s16x4 u0 = *(const s16x4*)(h + (size_t)j4 * HID + lane * 4);
    s16x4 u1 = *(const s16x4*)(h + (size_t)j5 * HID + lane * 4);
    s16x4 u2 = *(const s16x4*)(h + (size_t)j6 * HID + lane * 4);
    s16x4 u3 = *(const s16x4*)(h + (size_t)j7 * HID + lane * 4);
    float b0 = as_[(size_t)j4 * 4 + hq], b1 = as_[(size_t)j5 * 4 + hq];
    float b2 = as_[(size_t)j6 * 4 + hq], b3 = as_[(size_t)j7 * 4 + hq];
    int t0 = ssrc[min(p + 8, e1)],  t1 = ssrc[min(p + 9, e1)];
    int t2 = ssrc[min(p + 10, e1)], t3 = ssrc[min(p + 11, e1)];
    float l0 = a0 + ad2; l0 = fmaxf(l0, 0.2f * l0);
    float l1 = a1 + ad2; l1 = fmaxf(l1, 0.2f * l1);
    float l2 = a2 + ad2; l2 = fmaxf(l2, 0.2f * l2);
    float l3 = a3 + ad2; l3 = fmaxf(l3, 0.2f * l3);
    float w0 = __expf(l0), w1 = __expf(l1), w2 = __expf(l2), w3 = __expf(l3);
    sA_ += w0 + w2; sB_ += w1 + w3;
    #pragma unroll
    for (int c = 0; c < 4; c++){
      A[c]  += w0 * b2f((unsigned short)r0[c]);
      B[c]  += w1 * b2f((unsigned short)r1[c]);
      Cc[c] += w2 * b2f((unsigned short)r2[c]);
      D[c]  += w3 * b2f((unsigned short)r3[c]);
    }
    j0 = j4; j1 = j5; j2 = j6; j3 = j7;
    j4 = t0; j5 = t1; j6 = t2; j7 = t3;
    r0 = u0; r1 = u1; r2 = u2; r3 = u3;
    a0 = b0; a1 = b1; a2 = b2; a3 = b3;
  }
  int rem = end - p;                                   // 0..3
  if (rem > 0){
    float l = a0 + ad2; l = fmaxf(l, 0.2f * l);
    float w = __expf(l); sA_ += w;
    #pragma unroll
    for (int c = 0; c < 4; c++) A[c]  += w * b2f((unsigned short)r0[c]);
  }
  if (rem > 1){
    float l = a1 + ad2; l = fmaxf(l, 0.2f * l);
    float w = __expf(l); sB_ += w;
    #pragma unroll
    for (int c = 0; c < 4; c++) B[c]  += w * b2f((unsigned short)r1[c]);
  }
  if (rem > 2){
    float l = a2 + ad2; l = fmaxf(l, 0.2f * l);
    float w = __expf(l); sA_ += w;
    #pragma unroll
    for (int c = 0; c < 4; c++) Cc[c] += w * b2f((unsigned short)r2[c]);
  }

  float inv = 1.f / (sA_ + sB_ + 1e-16f);
  float4 bv = *(const float4*)(bias + lane * 4);
  float o0 = (A[0] + B[0] + Cc[0] + D[0]) * inv + bv.x;
  float o1 = (A[1] + B[1] + Cc[1] + D[1]) * inv + bv.y;
  float o2 = (A[2] + B[2] + Cc[2] + D[2]) * inv + bv.z;
  float o3 = (A[3] + B[3] + Cc[3] + D[3]) * inv + bv.w;
  o0 = o0 > 0.f ? o0 : (__expf(o0) - 1.f);
  o1 = o1 > 0.f ? o1 : (__expf(o1) - 1.f);
  o2 = o2 > 0.f ? o2 : (__expf(o2) - 1.f);
  o3 = o3 > 0.f ? o3 : (__expf(o3) - 1.f);
  s16x4 ov;
  ov[0] = (short)f2b(o0); ov[1] = (short)f2b(o1);
  ov[2] = (short)f2b(o2); ov[3] = (short)f2b(o3);
  *(s16x4*)(out + (size_t)wid * HID + lane * 4) = ov;
}

// ---------------- mean pool (plain atomics) + tiny head ----------------
__global__ __launch_bounds__(256) void k_pool(const unsigned short* __restrict__ X,
                                              float* __restrict__ pool){
  int b = blockIdx.x, c = threadIdx.x;
  int n0 = b * 64, n1 = min(n0 + 64, NN);
  float acc = 0.f;
  for (int n = n0; n < n1; n++) acc += b2f(X[(size_t)n * HID + c]);
  atomicAdd(&pool[c], acc);
}

__global__ void k_head(const float* __restrict__ pool, const float* __restrict__ hW,
                       const float* __restrict__ hb, float* __restrict__ outp){
  int o = threadIdx.x;             // 128
  float acc = hb[o];
  const float invN = 1.f / (float)NN;
  for (int c = 0; c < HID; c++) acc += pool[c] * invN * hW[c * OUTC + o];
  outp[o] = acc;
}

extern "C" void kernel_launch(void* const* d_in, const int* in_sizes, int n_in,
                              void* d_out, int out_size, void* d_ws, size_t ws_size,
                              hipStream_t stream){
  const float* x  = (const float*)d_in[0];
  const int* ei   = (const int*)d_in[1];
  const float* W[3]   = {(const float*)d_in[2],  (const float*)d_in[6],  (const float*)d_in[10]};
  const float* Asr[3] = {(const float*)d_in[3],  (const float*)d_in[7],  (const float*)d_in[11]};
  const float* Adt[3] = {(const float*)d_in[4],  (const float*)d_in[8],  (const float*)d_in[12]};
  const float* B[3]   = {(const float*)d_in[5],  (const float*)d_in[9],  (const float*)d_in[13]};
  const float* hW = (const float*)d_in[14];
  const float* hb = (const float*)d_in[15];

  char* w = (char*)d_ws; size_t o = 0;
  auto alloc = [&](size_t b) -> void* { void* p = w + o; o = (o + b + 255) & ~(size_t)255; return p; };
  int* cnt  = (int*)alloc((size_t)NN * 4);
  int* off  = (int*)alloc((size_t)NN * 4);
  int* ssrc = (int*)alloc((size_t)ET * 4);
  int* pos  = (int*)alloc((size_t)ET * 4);
  int* bsum = (int*)alloc((size_t)NB * 4);
  int* bbase= (int*)alloc((size_t)NB * 4);
  unsigned short* hbuf = (unsigned short*)alloc((size_t)NN * HID * 2);
  float* as_ = (float*)alloc((size_t)NN * 4 * 4);
  float* ad_ = (float*)alloc((size_t)NN * 4 * 4);
  unsigned short* X0 = (unsigned short*)alloc((size_t)NN * HID * 2);
  unsigned short* X1 = (unsigned short*)alloc((size_t)NN * HID * 2);
  unsigned short* WT1 = (unsigned short*)alloc((size_t)INC * HID * 2);
  unsigned short* WT2 = (unsigned short*)alloc((size_t)HID * HID * 2);
  unsigned short* WT3 = (unsigned short*)alloc((size_t)HID * HID * 2);
  float* pool = (float*)alloc(256 * 4);

  hipMemsetAsync(cnt, 0, (size_t)NN * 4, stream);
  k_init<<<GDEG + GTRP + 1, 256, 0, stream>>>(ei, cnt, pos, W[0], W[1], W[2], WT1, WT2, WT3, pool);
  k_blockscan<<<NB, 256, 0, stream>>>(cnt, off, bsum);
  k_scanb<<<1, 256, 0, stream>>>(bsum, bbase);
  k_scatter<<<GDEG, 256, 0, stream>>>(ei, off, bbase, pos, ssrc);

  const unsigned short* WTs[3] = {WT1, WT2, WT3};
  unsigned short* outbuf[3] = {X0, X1, X0};
  int Ks[3] = {INC, HID, HID};
  const void* Ain = (const void*)x;
  int gB = (NN + 63) / 64;          // pool blocks
  int gG = (NN + 31) / 32;          // gemm blocks (BM=32)
  for (int l = 0; l < 3; l++){
    if (l == 0) k_gemm_fused<true ><<<gG, 256, 0, stream>>>(Ain, WTs[l], Asr[l], Adt[l], hbuf, as_, ad_, NN, Ks[l]);
    else        k_gemm_fused<false><<<gG, 256, 0, stream>>>(Ain, WTs[l], Asr[l], Adt[l], hbuf, as_, ad_, NN, Ks[l]);
    k_aggregate<<<NN, 64, 0, stream>>>(off, bbase, ssrc, as_, ad_, hbuf, B[l], outbuf[l]);
    Ain = (const void*)outbuf[l];
  }
  k_pool<<<gB, 256, 0, stream>>>(X0, pool);
  k_head<<<1, 128, 0, stream>>>(pool, hW, hb, (float*)d_out);
}